// Round 6
// baseline (3925.081 us; speedup 1.0000x reference)
//
#include <hip/hip_runtime.h>

typedef __bf16 bf16x8 __attribute__((ext_vector_type(8)));
typedef float  f32x4  __attribute__((ext_vector_type(4)));
typedef __attribute__((address_space(3))) unsigned char lds_b;
typedef __attribute__((address_space(1))) const unsigned char glb_b;

__device__ __forceinline__ float rcp_(float x) { return __builtin_amdgcn_rcpf(x); }
__device__ __forceinline__ float bf2f(unsigned short u) { return __uint_as_float(((unsigned)u) << 16); }
__device__ __forceinline__ void gll16(const void* g, void* l) {
  __builtin_amdgcn_global_load_lds((glb_b*)g, (lds_b*)l, 16, 0, 0);
}

// ---------------------------------------------------------------------------
// prep_wih: natural-order bf16 copy of Wih rows + bias fold (bih + bhh for r,z)
// ---------------------------------------------------------------------------
__global__ __launch_bounds__(256) void prep_wih(
    const float* __restrict__ Wih, const float* __restrict__ bsrc, int Kin,
    __bf16* __restrict__ wih_o, float* __restrict__ bih_o)
{
  int R = blockIdx.x;                 // 0..1535 natural: dir*768 + gt*256 + d
  const float* src = Wih + (size_t)R * Kin;
  __bf16* dst = wih_o + (size_t)R * Kin;
  for (int k = threadIdx.x; k < Kin; k += 256) dst[k] = (__bf16)src[k];
  if (threadIdx.x == 0) {
    int dir = R / 768, g = R % 768, gt = g >> 8;
    float bih = bsrc[(dir * 2 + 0) * 768 + g];
    float bhh = bsrc[(dir * 2 + 1) * 768 + g];
    bih_o[R] = bih + (gt < 2 ? bhh : 0.0f);
  }
}

// ---------------------------------------------------------------------------
// prep_whh: wstream[(dir*4+hs)*49152 + ((w*3+gt)*8+ks)*512 + lane*8 + e]
//         = Whh[dir*768 + gt*256 + hs*64 + w*16 + (lane&15)][ks*32+(lane>>4)*8+e]
// grid 96 = dir(2) x hs(4) x w(4) x gt(3)
// ---------------------------------------------------------------------------
__global__ __launch_bounds__(256) void prep_whh(
    const float* __restrict__ Whh, __bf16* __restrict__ wstream_o)
{
  int b = blockIdx.x;
  int gt = b % 3, w = (b / 3) % 4, hs = (b / 12) % 4, dir = b / 48;
  for (int i = 0; i < 16; ++i) {
    int f = i * 256 + threadIdx.x;    // 0..4095
    int ks = f >> 9, lane = (f >> 3) & 63, e = f & 7;
    int l15 = lane & 15, lq = lane >> 4;
    int row = dir * 768 + gt * 256 + hs * 64 + w * 16 + l15;
    float v = Whh[(size_t)row * 256 + ks * 32 + lq * 8 + e];
    wstream_o[(size_t)(dir * 4 + hs) * 49152 + ((w * 3 + gt) * 8 + ks) * 512 + lane * 8 + e] = (__bf16)v;
  }
}

__global__ __launch_bounds__(256) void k_reset(int* flags) {
  flags[blockIdx.x * 256 + threadIdx.x] = 0;
}

// ---------------------------------------------------------------------------
// a[b,t] = c[b,t,:]·wc   and   e[b,j] = q[b,j,:]·wq    (one wave per dot)
// ---------------------------------------------------------------------------
__global__ __launch_bounds__(256) void k_dots(
    const float* __restrict__ c, const float* __restrict__ q,
    const float* __restrict__ Ws, float* __restrict__ a_g, float* __restrict__ e_g)
{
  const int wid = blockIdx.x * 4 + (threadIdx.x >> 6);
  const int lane = threadIdx.x & 63;
  const float* x; const float* wv; float* o;
  if (wid < 4096) { x = q + (size_t)wid * 512; wv = Ws + 512; o = e_g + wid; }
  else { int id = wid - 4096; x = c + (size_t)id * 512; wv = Ws; o = a_g + id; }
  float s = 0.f;
  #pragma unroll
  for (int i = 0; i < 8; ++i) s = fmaf(x[lane * 8 + i], wv[lane * 8 + i], s);
  #pragma unroll
  for (int off = 32; off; off >>= 1) s += __shfl_xor(s, off);
  if (lane == 0) *o = s;
}

// ---------------------------------------------------------------------------
// Fused attention main: per (b, t-half).
// ---------------------------------------------------------------------------
__global__ __launch_bounds__(512) void k_att_main(
    const float* __restrict__ c, const float* __restrict__ q,
    const float* __restrict__ Ws, const float* __restrict__ a_g,
    const float* __restrict__ e_g, float* __restrict__ smax_g,
    __bf16* __restrict__ G)
{
  constexpr int QSTR = 513;
  __shared__ float q_s[64 * QSTR];
  __shared__ float c_s[512], cw_s[512], sP[64], e_s[64], sred[512];
  const int b = blockIdx.y, th = blockIdx.x;
  const int tid = threadIdx.x;
  const float* qb = q + (size_t)b * 64 * 512;
  for (int i = tid; i < 64 * 512; i += 512) q_s[(i >> 9) * QSTR + (i & 511)] = qb[i];
  if (tid < 64) e_s[tid] = e_g[b * 64 + tid];
  __syncthreads();
  const int p = tid >> 6;
  const int j = tid & 63;
  for (int tt = 0; tt < 128; ++tt) {
    const int t = th * 128 + tt;
    float cv = c[((size_t)b * 256 + t) * 512 + tid];
    c_s[tid] = cv;
    cw_s[tid] = cv * Ws[1024 + tid];
    __syncthreads();
    {
      const float* qrow = &q_s[j * QSTR + p * 64];
      const float* cw = &cw_s[p * 64];
      float s = 0.f;
      #pragma unroll
      for (int i = 0; i < 64; ++i) s = fmaf(cw[i], qrow[i], s);
      sred[p * 64 + j] = s;
    }
    __syncthreads();
    if (tid < 64) {
      float s = sred[tid] + sred[64 + tid] + sred[128 + tid] + sred[192 + tid]
              + sred[256 + tid] + sred[320 + tid] + sred[384 + tid] + sred[448 + tid];
      s += a_g[b * 256 + t] + e_s[tid];
      float m = s;
      #pragma unroll
      for (int off = 32; off; off >>= 1) m = fmaxf(m, __shfl_xor(m, off));
      float e = __expf(s - m);
      float sum = e;
      #pragma unroll
      for (int off = 32; off; off >>= 1) sum += __shfl_xor(sum, off);
      sP[tid] = e / sum;
      if (tid == 0) smax_g[b * 256 + t] = m;
    }
    __syncthreads();
    {
      float acc = 0.f;
      #pragma unroll 8
      for (int jj = 0; jj < 64; ++jj) acc = fmaf(sP[jj], q_s[jj * QSTR + tid], acc);
      float cval = c_s[tid];
      __bf16* Gr = G + ((size_t)b * 256 + t) * 2560;
      Gr[tid]        = (__bf16)cval;
      Gr[512 + tid]  = (__bf16)acc;
      Gr[1024 + tid] = (__bf16)(cval * acc);
    }
    __syncthreads();
  }
}

// ---------------------------------------------------------------------------
// q2c tail
// ---------------------------------------------------------------------------
__global__ __launch_bounds__(256) void k_att_tail(
    const float* __restrict__ c, const float* __restrict__ smax_g,
    __bf16* __restrict__ G)
{
  __shared__ float w_s[256];
  __shared__ float red[8];
  const int b = blockIdx.x, tid = threadIdx.x;
  const int lane = tid & 63, wv = tid >> 6;
  float v = smax_g[b * 256 + tid];
  float m = v;
  #pragma unroll
  for (int off = 32; off; off >>= 1) m = fmaxf(m, __shfl_xor(m, off));
  if (lane == 0) red[wv] = m;
  __syncthreads();
  m = fmaxf(fmaxf(red[0], red[1]), fmaxf(red[2], red[3]));
  float e = __expf(v - m);
  float s = e;
  #pragma unroll
  for (int off = 32; off; off >>= 1) s += __shfl_xor(s, off);
  if (lane == 0) red[4 + wv] = s;
  __syncthreads();
  s = red[4] + red[5] + red[6] + red[7];
  w_s[tid] = e / s;
  __syncthreads();
  float q0 = 0.f, q1 = 0.f;
  for (int t = 0; t < 256; ++t) {
    const float* cr = c + ((size_t)b * 256 + t) * 512;
    q0 = fmaf(w_s[t], cr[tid], q0);
    q1 = fmaf(w_s[t], cr[tid + 256], q1);
  }
  for (int t = 0; t < 256; ++t) {
    const float* cr = c + ((size_t)b * 256 + t) * 512;
    __bf16* Gr = G + ((size_t)b * 256 + t) * 2560 + 1536;
    Gr[tid]       = (__bf16)(cr[tid] * q0);
    Gr[tid + 256] = (__bf16)(cr[tid + 256] * q1);
  }
}

// ---------------------------------------------------------------------------
// GEMM: C[M,1536] = A[M,K] @ Bw[1536,K]^T + bias, bf16 out.
// 128x128, BK=32, 4 waves, global_load_lds width-16 staging (m97 pattern),
// linear [128][32] LDS tiles.
// ---------------------------------------------------------------------------
__global__ __launch_bounds__(256) void gemm_bt(
    const __bf16* __restrict__ A, int lda,
    const __bf16* __restrict__ Bw, const float* __restrict__ bias,
    __bf16* __restrict__ C, int K)
{
  __shared__ __align__(16) __bf16 As[4096], Bs[4096];   // [128][32]
  const int tid = threadIdx.x;
  const int lane = tid & 63, w = tid >> 6;
  const int l15 = lane & 15, lq = lane >> 4;
  const int wm = w >> 1, wn = w & 1;
  const size_t bm = (size_t)blockIdx.x * 128;
  const size_t bn = (size_t)blockIdx.y * 128;
  const int srow = lane >> 2, scol = (lane & 3) * 8;    // stage: lane -> row/colblk
  f32x4 acc[4][4] = {};
  const int nkt = K >> 5;
  for (int kt = 0; kt < nkt; ++kt) {
    const int ko = kt * 32;
    __syncthreads();                       // prior frag reads done
    #pragma unroll
    for (int j = 0; j < 2; ++j) {
      const int rb = (j * 4 + w) * 16;     // row base (uniform per wave)
      gll16(A + (bm + rb + srow) * (size_t)lda + ko + scol, &As[rb * 32]);
      gll16(Bw + (bn + rb + srow) * (size_t)K + ko + scol, &Bs[rb * 32]);
    }
    __syncthreads();                       // drains vmcnt -> tiles ready
    bf16x8 af[4], bfv[4];
    #pragma unroll
    for (int f = 0; f < 4; ++f) {
      af[f]  = *(const bf16x8*)&As[(wm * 64 + f * 16 + l15) * 32 + lq * 8];
      bfv[f] = *(const bf16x8*)&Bs[(wn * 64 + f * 16 + l15) * 32 + lq * 8];
    }
    #pragma unroll
    for (int fm = 0; fm < 4; ++fm)
      #pragma unroll
      for (int fn = 0; fn < 4; ++fn)
        acc[fm][fn] = __builtin_amdgcn_mfma_f32_16x16x32_bf16(af[fm], bfv[fn], acc[fm][fn], 0, 0, 0);
  }
  float bv[4];
  #pragma unroll
  for (int fn = 0; fn < 4; ++fn) bv[fn] = bias[bn + wn * 64 + fn * 16 + l15];
  #pragma unroll
  for (int fm = 0; fm < 4; ++fm)
    #pragma unroll
    for (int fn = 0; fn < 4; ++fn)
      #pragma unroll
      for (int r = 0; r < 4; ++r) {
        size_t row = bm + wm * 64 + fm * 16 + lq * 4 + r;
        size_t col = bn + wn * 64 + fn * 16 + l15;
        C[row * 1536 + col] = (__bf16)(acc[fm][fn][r] + bv[fn]);
      }
}

// ---------------------------------------------------------------------------
// GRU recurrence v6: hidden-split. 32 WGs of 256 thr: wg = hs*8 + u,
// u = bgroup*2 + dir (partners {hs=0..3} of one u share an XCD under %8
// round-robin). Each WG: 64 hidden units x 16 batches; its 96KB Whh slice
// lives ENTIRELY in LDS -> zero per-step weight streaming. Per step the 4
// partners exchange h slices (2KB) via parity-double-buffered global hx with
// release/acquire flags (AGENT scope). gi natural layout, prefetched 1 step.
// ---------------------------------------------------------------------------
#define SPIN_CAP (1u << 24)
__global__ __launch_bounds__(256) void gru_rec2(
    const __bf16* __restrict__ gi, const __bf16* __restrict__ wstream,
    const float* __restrict__ bsrc, __bf16* hx, int* flags,
    __bf16* __restrict__ ys, int ys_stride, float* __restrict__ out_final)
{
  constexpr int HSTR = 264;
  __shared__ __align__(16) __bf16 wlds[49152];          // 96 KB slice
  __shared__ __align__(16) __bf16 hl[2][16 * HSTR];     // 16.9 KB
  const int tid = threadIdx.x;
  const int w = tid >> 6, lane = tid & 63;
  const int l15 = lane & 15, lq = lane >> 4;
  const int wg = blockIdx.x;
  const int u = wg & 7, hs = wg >> 3;
  const int dir = u & 1, bg = u >> 1;
  const int b0 = bg * 16;
  const int dglob = hs * 64 + w * 16 + l15;             // this lane's hidden unit

  { // weights -> LDS (one-time)
    const __bf16* srcw = wstream + (size_t)(dir * 4 + hs) * 49152;
    for (int i = tid * 8; i < 49152; i += 256 * 8)
      *(bf16x8*)&wlds[i] = *(const bf16x8*)(srcw + i);
  }
  for (int i = tid; i < 2 * 16 * HSTR; i += 256) (&hl[0][0])[i] = (__bf16)0.0f;

  const float bhn = bsrc[(dir * 2 + 1) * 768 + 512 + dglob];
  const unsigned short* gsh = (const unsigned short*)gi;
  size_t gbase[4];
  #pragma unroll
  for (int r = 0; r < 4; ++r)
    gbase[r] = ((size_t)(b0 + lq * 4 + r) * 256) * 1536 + dir * 768 + dglob;

  __bf16* hx_me_base = hx + ((size_t)u * 4 + hs) * 1024;  // + parity*32768
  int* flag_me = flags + (u * 4 + hs) * 64;
  const int crow = tid >> 4, c8 = tid & 15;             // exchange-copy mapping

  __syncthreads();

  // prologue gi load (step 0)
  unsigned short gr[4], gz[4], gn[4];
  {
    const int t0 = dir ? 255 : 0;
    #pragma unroll
    for (int r = 0; r < 4; ++r) {
      size_t p = gbase[r] + (size_t)t0 * 1536;
      gr[r] = gsh[p]; gz[r] = gsh[p + 256]; gn[r] = gsh[p + 512];
    }
  }

  float hprev[4] = {0.f, 0.f, 0.f, 0.f};
  int cur = 0;
  for (int s = 0; s < 256; ++s) {
    const int t = dir ? 255 - s : s;
    // prefetch next step's gi
    unsigned short nr[4], nz[4], nn[4];
    if (s < 255) {
      const int tn = dir ? 254 - s : s + 1;
      #pragma unroll
      for (int r = 0; r < 4; ++r) {
        size_t p = gbase[r] + (size_t)tn * 1536;
        nr[r] = gsh[p]; nz[r] = gsh[p + 256]; nn[r] = gsh[p + 512];
      }
    }
    // gh = h @ Whh_slice^T : 24 MFMAs, all operands LDS-resident
    f32x4 acc[3] = {};
    const __bf16* hb_ = &hl[cur][l15 * HSTR + lq * 8];
    #pragma unroll
    for (int ks = 0; ks < 8; ++ks) {
      bf16x8 af = *(const bf16x8*)(hb_ + ks * 32);
      #pragma unroll
      for (int gt = 0; gt < 3; ++gt) {
        bf16x8 wf = *(const bf16x8*)&wlds[((w * 3 + gt) * 8 + ks) * 512 + lane * 8];
        acc[gt] = __builtin_amdgcn_mfma_f32_16x16x32_bf16(af, wf, acc[gt], 0, 0, 0);
      }
    }
    // gates: 4 outputs/lane (batches lq*4+r, hidden dglob)
    const int parW = (s + 1) & 1;
    __bf16* hx_w = hx_me_base + parW * 32768;
    #pragma unroll
    for (int r = 0; r < 4; ++r) {
      float eR = __expf(-(bf2f(gr[r]) + acc[0][r]));
      float rg = rcp_(1.0f + eR);
      float eZ = __expf(-(bf2f(gz[r]) + acc[1][r]));
      float zg = rcp_(1.0f + eZ);
      float a  = bf2f(gn[r]) + rg * (acc[2][r] + bhn);
      a = fminf(fmaxf(a, -15.0f), 15.0f);
      float eN = __expf(-2.0f * a);
      float ng = (1.0f - eN) * rcp_(1.0f + eN);
      float h = ng + zg * (hprev[r] - ng);
      hprev[r] = h;
      hl[cur ^ 1][(lq * 4 + r) * HSTR + dglob] = (__bf16)h;
      if (s < 255) hx_w[(lq * 4 + r) * 64 + w * 16 + l15] = (__bf16)h;
      gr[r] = nr[r]; gz[r] = nz[r]; gn[r] = nn[r];
    }
    if (s < 255) {
      asm volatile("s_waitcnt vmcnt(0)" ::: "memory");   // own hx stores complete
      __syncthreads();                                   // #1 own slice in LDS
      if (ys) {  // overlapped with flag/spin
        uint2 v = *(const uint2*)&hl[cur ^ 1][crow * HSTR + hs * 64 + c8 * 4];
        *(uint2*)(ys + ((size_t)(b0 + crow) * 256 + t) * ys_stride + dir * 256 + hs * 64 + c8 * 4) = v;
      }
      if (tid == 0)
        __hip_atomic_store(flag_me, s + 1, __ATOMIC_RELEASE, __HIP_MEMORY_SCOPE_AGENT);
      if (tid >= 253) {
        int pi = tid - 253;
        int p = pi + (pi >= hs);
        int* pf = flags + (u * 4 + p) * 64;
        unsigned spins = 0; int v;
        do { v = __hip_atomic_load(pf, __ATOMIC_ACQUIRE, __HIP_MEMORY_SCOPE_AGENT); }
        while (v < s + 1 && ++spins < SPIN_CAP);
      }
      __syncthreads();                                   // #2 partners flagged
      const __bf16* hx_r = hx + parW * 32768;
      #pragma unroll
      for (int pi = 0; pi < 3; ++pi) {
        int p = pi + (pi >= hs);
        uint2 v = *(const uint2*)(hx_r + ((size_t)u * 4 + p) * 1024 + crow * 64 + c8 * 4);
        *(uint2*)&hl[cur ^ 1][crow * HSTR + p * 64 + c8 * 4] = v;
      }
      __syncthreads();                                   // #3 full h ready
    } else {
      __syncthreads();
      if (ys) {
        uint2 v = *(const uint2*)&hl[cur ^ 1][crow * HSTR + hs * 64 + c8 * 4];
        *(uint2*)(ys + ((size_t)(b0 + crow) * 256 + t) * ys_stride + dir * 256 + hs * 64 + c8 * 4) = v;
      }
    }
    cur ^= 1;
  }
  if (!ys) {
    #pragma unroll
    for (int r = 0; r < 4; ++r)
      out_final[(size_t)(b0 + lq * 4 + r) * 512 + (dir ? 0 : 256) + dglob] = hprev[r];
  }
}

// ---------------------------------------------------------------------------
extern "C" void kernel_launch(void* const* d_in, const int* in_sizes, int n_in,
                              void* d_out, int out_size, void* d_ws, size_t ws_size,
                              hipStream_t stream) {
  (void)in_sizes; (void)n_in; (void)out_size; (void)ws_size;
  const float* c  = (const float*)d_in[0];
  const float* q  = (const float*)d_in[1];
  const float* Ws = (const float*)d_in[4];
  const float* w_ih[4] = { (const float*)d_in[5], (const float*)d_in[8],
                           (const float*)d_in[11], (const float*)d_in[14] };
  const float* w_hh[4] = { (const float*)d_in[6], (const float*)d_in[9],
                           (const float*)d_in[12], (const float*)d_in[15] };
  const float* b_l[4]  = { (const float*)d_in[7], (const float*)d_in[10],
                           (const float*)d_in[13], (const float*)d_in[16] };
  const int Kin[4] = {2048, 512, 2560, 512};

  char* ws = (char*)d_ws;
  size_t off = 0;
  auto alloc = [&](size_t bytes) -> void* {
    void* p = ws + off; off += (bytes + 255) & ~(size_t)255; return p;
  };
  __bf16* Gbuf = (__bf16*)alloc((size_t)16384 * 2560 * 2);  // [G | M] bf16
  __bf16* gi   = (__bf16*)alloc((size_t)16384 * 1536 * 2);  // natural gate-major
  __bf16* m0   = (__bf16*)alloc((size_t)16384 * 512 * 2);
  __bf16* r0   = (__bf16*)alloc((size_t)16384 * 512 * 2);
  __bf16* wihp[4]; __bf16* wstr[4]; float* bihp[4];
  for (int l = 0; l < 4; ++l) {
    wihp[l] = (__bf16*)alloc((size_t)1536 * Kin[l] * 2);
    wstr[l] = (__bf16*)alloc((size_t)1536 * 256 * 2);   // slice-major stream
    bihp[l] = (float*)alloc(1536 * 4);
  }
  float* e_g   = (float*)alloc(4096 * 4);
  float* a_g   = (float*)alloc(16384 * 4);
  float* smax  = (float*)alloc(16384 * 4);
  __bf16* hx   = (__bf16*)alloc((size_t)2 * 32768 * 2);  // parity x 8u x 4hs x 16 x 64
  int*    flags = (int*)alloc(2048 * 4);

  for (int l = 0; l < 4; ++l) {
    prep_wih<<<1536, 256, 0, stream>>>(w_ih[l], b_l[l], Kin[l], wihp[l], bihp[l]);
    prep_whh<<<96, 256, 0, stream>>>(w_hh[l], wstr[l]);
  }
  k_dots<<<5120, 256, 0, stream>>>(c, q, Ws, a_g, e_g);
  k_att_main<<<dim3(2, 64), 512, 0, stream>>>(c, q, Ws, a_g, e_g, smax, Gbuf);
  k_att_tail<<<64, 256, 0, stream>>>(c, smax, Gbuf);

  // layer mod0: G(2048) -> m0
  gemm_bt<<<dim3(128, 12), 256, 0, stream>>>(Gbuf, 2560, wihp[0], bihp[0], gi, 2048);
  k_reset<<<8, 256, 0, stream>>>(flags);
  gru_rec2<<<32, 256, 0, stream>>>(gi, wstr[0], b_l[0], hx, flags, m0, 512, nullptr);
  // layer mod1: m0(512) -> M (into Gbuf cols 2048:2560)
  gemm_bt<<<dim3(128, 12), 256, 0, stream>>>(m0, 512, wihp[1], bihp[1], gi, 512);
  k_reset<<<8, 256, 0, stream>>>(flags);
  gru_rec2<<<32, 256, 0, stream>>>(gi, wstr[1], b_l[1], hx, flags, Gbuf + 2048, 2560, nullptr);
  // layer rep0: [G|M](2560) -> r0
  gemm_bt<<<dim3(128, 12), 256, 0, stream>>>(Gbuf, 2560, wihp[2], bihp[2], gi, 2560);
  k_reset<<<8, 256, 0, stream>>>(flags);
  gru_rec2<<<32, 256, 0, stream>>>(gi, wstr[2], b_l[2], hx, flags, r0, 512, nullptr);
  // layer rep1: r0(512) -> final h only
  gemm_bt<<<dim3(128, 12), 256, 0, stream>>>(r0, 512, wihp[3], bihp[3], gi, 512);
  k_reset<<<8, 256, 0, stream>>>(flags);
  gru_rec2<<<32, 256, 0, stream>>>(gi, wstr[3], b_l[3], hx, flags, nullptr, 0, (float*)d_out);
}

// Round 7
// 2748.537 us; speedup vs baseline: 1.4281x; 1.4281x over previous
//
#include <hip/hip_runtime.h>

typedef __bf16 bf16x8 __attribute__((ext_vector_type(8)));
typedef float  f32x4  __attribute__((ext_vector_type(4)));
typedef __attribute__((address_space(3))) unsigned char lds_b;
typedef __attribute__((address_space(1))) const unsigned char glb_b;

__device__ __forceinline__ float rcp_(float x) { return __builtin_amdgcn_rcpf(x); }
__device__ __forceinline__ float bflo(unsigned u) { return __uint_as_float(u << 16); }
__device__ __forceinline__ float bfhi(unsigned u) { return __uint_as_float(u & 0xffff0000u); }
__device__ __forceinline__ void gll16(const void* g, void* l) {
  __builtin_amdgcn_global_load_lds((glb_b*)g, (lds_b*)l, 16, 0, 0);
}

// ---------------------------------------------------------------------------
// Weight prep (v5 layout). wstream: fragment-major, per-wave-coalesced:
//   chunk c = ks*6 + dg*3 + gt ; flat idx (((dir*8+w)*48+c)*64 + lane)*8 + e
// Wih rows reordered to r'' = w*96 + l15*6 + dg*3 + gt (gate-packed gi).
// b_hh for r,z folded into GEMM bias; bhh_o keeps raw b_hh (n-gate use).
// ---------------------------------------------------------------------------
__global__ __launch_bounds__(256) void prep_layer(
    const float* __restrict__ Wih, const float* __restrict__ Whh,
    const float* __restrict__ bsrc, int Kin,
    __bf16* __restrict__ wih_o, __bf16* __restrict__ wstream_o,
    float* __restrict__ bih_o, float* __restrict__ bhh_o)
{
  int R = blockIdx.x;                 // 0..1535 (dir-major, r''-order)
  int dir = (R >= 768) ? 1 : 0;
  int rp = R - dir * 768;
  int w = rp / 96, rem = rp % 96;
  int l15 = rem / 6, gx = rem % 6;
  int dg = gx / 3, gt = gx % 3;
  int d = w * 32 + dg * 16 + l15;
  int g = gt * 256 + d;
  const float* src = Wih + ((size_t)dir * 768 + g) * Kin;
  __bf16* dst = wih_o + (size_t)R * Kin;
  for (int k = threadIdx.x; k < Kin; k += 256) dst[k] = (__bf16)src[k];
  {
    int k = threadIdx.x;              // 0..255
    int ks = k >> 5, lq = (k >> 3) & 3, e = k & 7;
    int c = ks * 6 + dg * 3 + gt;
    size_t di = ((((size_t)dir * 8 + w) * 48 + c) * 64 + (lq * 16 + l15)) * 8 + e;
    wstream_o[di] = (__bf16)Whh[((size_t)dir * 768 + g) * 256 + k];
  }
  if (threadIdx.x == 0) {
    float bih = bsrc[(dir * 2 + 0) * 768 + g];
    float bhh = bsrc[(dir * 2 + 1) * 768 + g];
    bih_o[R] = bih + (gt < 2 ? bhh : 0.0f);
    bhh_o[R] = bhh;
  }
}

// ---------------------------------------------------------------------------
// a[b,t] = c[b,t,:]·wc   and   e[b,j] = q[b,j,:]·wq    (one wave per dot)
// ---------------------------------------------------------------------------
__global__ __launch_bounds__(256) void k_dots(
    const float* __restrict__ c, const float* __restrict__ q,
    const float* __restrict__ Ws, float* __restrict__ a_g, float* __restrict__ e_g)
{
  const int wid = blockIdx.x * 4 + (threadIdx.x >> 6);
  const int lane = threadIdx.x & 63;
  const float* x; const float* wv; float* o;
  if (wid < 4096) { x = q + (size_t)wid * 512; wv = Ws + 512; o = e_g + wid; }
  else { int id = wid - 4096; x = c + (size_t)id * 512; wv = Ws; o = a_g + id; }
  float s = 0.f;
  #pragma unroll
  for (int i = 0; i < 8; ++i) s = fmaf(x[lane * 8 + i], wv[lane * 8 + i], s);
  #pragma unroll
  for (int off = 32; off; off >>= 1) s += __shfl_xor(s, off);
  if (lane == 0) *o = s;
}

// ---------------------------------------------------------------------------
// Fused attention main: per (b, t-half).
// ---------------------------------------------------------------------------
__global__ __launch_bounds__(512) void k_att_main(
    const float* __restrict__ c, const float* __restrict__ q,
    const float* __restrict__ Ws, const float* __restrict__ a_g,
    const float* __restrict__ e_g, float* __restrict__ smax_g,
    __bf16* __restrict__ G)
{
  constexpr int QSTR = 513;
  __shared__ float q_s[64 * QSTR];
  __shared__ float c_s[512], cw_s[512], sP[64], e_s[64], sred[512];
  const int b = blockIdx.y, th = blockIdx.x;
  const int tid = threadIdx.x;
  const float* qb = q + (size_t)b * 64 * 512;
  for (int i = tid; i < 64 * 512; i += 512) q_s[(i >> 9) * QSTR + (i & 511)] = qb[i];
  if (tid < 64) e_s[tid] = e_g[b * 64 + tid];
  __syncthreads();
  const int p = tid >> 6;
  const int j = tid & 63;
  for (int tt = 0; tt < 128; ++tt) {
    const int t = th * 128 + tt;
    float cv = c[((size_t)b * 256 + t) * 512 + tid];
    c_s[tid] = cv;
    cw_s[tid] = cv * Ws[1024 + tid];
    __syncthreads();
    {
      const float* qrow = &q_s[j * QSTR + p * 64];
      const float* cw = &cw_s[p * 64];
      float s = 0.f;
      #pragma unroll
      for (int i = 0; i < 64; ++i) s = fmaf(cw[i], qrow[i], s);
      sred[p * 64 + j] = s;
    }
    __syncthreads();
    if (tid < 64) {
      float s = sred[tid] + sred[64 + tid] + sred[128 + tid] + sred[192 + tid]
              + sred[256 + tid] + sred[320 + tid] + sred[384 + tid] + sred[448 + tid];
      s += a_g[b * 256 + t] + e_s[tid];
      float m = s;
      #pragma unroll
      for (int off = 32; off; off >>= 1) m = fmaxf(m, __shfl_xor(m, off));
      float e = __expf(s - m);
      float sum = e;
      #pragma unroll
      for (int off = 32; off; off >>= 1) sum += __shfl_xor(sum, off);
      sP[tid] = e / sum;
      if (tid == 0) smax_g[b * 256 + t] = m;
    }
    __syncthreads();
    {
      float acc = 0.f;
      #pragma unroll 8
      for (int jj = 0; jj < 64; ++jj) acc = fmaf(sP[jj], q_s[jj * QSTR + tid], acc);
      float cval = c_s[tid];
      __bf16* Gr = G + ((size_t)b * 256 + t) * 2560;
      Gr[tid]        = (__bf16)cval;
      Gr[512 + tid]  = (__bf16)acc;
      Gr[1024 + tid] = (__bf16)(cval * acc);
    }
    __syncthreads();
  }
}

// ---------------------------------------------------------------------------
// q2c tail
// ---------------------------------------------------------------------------
__global__ __launch_bounds__(256) void k_att_tail(
    const float* __restrict__ c, const float* __restrict__ smax_g,
    __bf16* __restrict__ G)
{
  __shared__ float w_s[256];
  __shared__ float red[8];
  const int b = blockIdx.x, tid = threadIdx.x;
  const int lane = tid & 63, wv = tid >> 6;
  float v = smax_g[b * 256 + tid];
  float m = v;
  #pragma unroll
  for (int off = 32; off; off >>= 1) m = fmaxf(m, __shfl_xor(m, off));
  if (lane == 0) red[wv] = m;
  __syncthreads();
  m = fmaxf(fmaxf(red[0], red[1]), fmaxf(red[2], red[3]));
  float e = __expf(v - m);
  float s = e;
  #pragma unroll
  for (int off = 32; off; off >>= 1) s += __shfl_xor(s, off);
  if (lane == 0) red[4 + wv] = s;
  __syncthreads();
  s = red[4] + red[5] + red[6] + red[7];
  w_s[tid] = e / s;
  __syncthreads();
  float q0 = 0.f, q1 = 0.f;
  for (int t = 0; t < 256; ++t) {
    const float* cr = c + ((size_t)b * 256 + t) * 512;
    q0 = fmaf(w_s[t], cr[tid], q0);
    q1 = fmaf(w_s[t], cr[tid + 256], q1);
  }
  for (int t = 0; t < 256; ++t) {
    const float* cr = c + ((size_t)b * 256 + t) * 512;
    __bf16* Gr = G + ((size_t)b * 256 + t) * 2560 + 1536;
    Gr[tid]       = (__bf16)(cr[tid] * q0);
    Gr[tid + 256] = (__bf16)(cr[tid + 256] * q1);
  }
}

// ---------------------------------------------------------------------------
// GEMM: C[M,1536] = A[M,K] @ Bw[1536,K]^T + bias, bf16 out.
// 128x128, BK=32, 4 waves, global_load_lds width-16 staging, linear [128][32].
// ---------------------------------------------------------------------------
__global__ __launch_bounds__(256) void gemm_bt(
    const __bf16* __restrict__ A, int lda,
    const __bf16* __restrict__ Bw, const float* __restrict__ bias,
    __bf16* __restrict__ C, int K)
{
  __shared__ __align__(16) __bf16 As[4096], Bs[4096];   // [128][32]
  const int tid = threadIdx.x;
  const int lane = tid & 63, w = tid >> 6;
  const int l15 = lane & 15, lq = lane >> 4;
  const int wm = w >> 1, wn = w & 1;
  const size_t bm = (size_t)blockIdx.x * 128;
  const size_t bn = (size_t)blockIdx.y * 128;
  const int srow = lane >> 2, scol = (lane & 3) * 8;
  f32x4 acc[4][4] = {};
  const int nkt = K >> 5;
  for (int kt = 0; kt < nkt; ++kt) {
    const int ko = kt * 32;
    __syncthreads();
    #pragma unroll
    for (int j = 0; j < 2; ++j) {
      const int rb = (j * 4 + w) * 16;
      gll16(A + (bm + rb + srow) * (size_t)lda + ko + scol, &As[rb * 32]);
      gll16(Bw + (bn + rb + srow) * (size_t)K + ko + scol, &Bs[rb * 32]);
    }
    __syncthreads();
    bf16x8 af[4], bfv[4];
    #pragma unroll
    for (int f = 0; f < 4; ++f) {
      af[f]  = *(const bf16x8*)&As[(wm * 64 + f * 16 + l15) * 32 + lq * 8];
      bfv[f] = *(const bf16x8*)&Bs[(wn * 64 + f * 16 + l15) * 32 + lq * 8];
    }
    #pragma unroll
    for (int fm = 0; fm < 4; ++fm)
      #pragma unroll
      for (int fn = 0; fn < 4; ++fn)
        acc[fm][fn] = __builtin_amdgcn_mfma_f32_16x16x32_bf16(af[fm], bfv[fn], acc[fm][fn], 0, 0, 0);
  }
  float bv[4];
  #pragma unroll
  for (int fn = 0; fn < 4; ++fn) bv[fn] = bias[bn + wn * 64 + fn * 16 + l15];
  #pragma unroll
  for (int fm = 0; fm < 4; ++fm)
    #pragma unroll
    for (int fn = 0; fn < 4; ++fn)
      #pragma unroll
      for (int r = 0; r < 4; ++r) {
        size_t row = bm + wm * 64 + fm * 16 + lq * 4 + r;
        size_t col = bn + wn * 64 + fn * 16 + l15;
        C[row * 1536 + col] = (__bf16)(acc[fm][fn][r] + bv[fn]);
      }
}

// ---------------------------------------------------------------------------
// GRU recurrence v7: ALL 48 weight chunks resident — 17 in LDS (136KB),
// 31 pinned in VGPRs via opaque-asm redefinition (defeats rematerialization;
// rounds 2-3 showed the allocator otherwise re-loads every step). Zero
// per-step weight streaming. rcp gates, lgkm-only barrier, coalesced ys.
// Truth indicator: VGPR_Count must be ~220 (128 => pin failed).
// ---------------------------------------------------------------------------
#define GRU_NL 17
#define GRU_NV 31
#define GRU_LDS_BYTES (GRU_NL * 8 * 1024 + 16896)
__global__ __launch_bounds__(512) void gru_rec(
    const __bf16* __restrict__ gi, const __bf16* __restrict__ wstream,
    const float* __restrict__ bhh, __bf16* __restrict__ ys, int ys_stride,
    float* __restrict__ out_final)
{
  constexpr int HSTR = 264;
  extern __shared__ __align__(16) char smem[];
  __bf16* wlds = (__bf16*)smem;                          // GRU_NL KB per wave
  __bf16* hl   = (__bf16*)(smem + GRU_NL * 8 * 1024);    // 2 * 16*HSTR bf16
  const int tid = threadIdx.x;
  const int w = tid >> 6, lane = tid & 63;
  const int l15 = lane & 15, lq = lane >> 4;
  const int dir = blockIdx.y;
  const int b0 = blockIdx.x * 16;

  for (int i = tid; i < 2 * 16 * HSTR; i += 512) hl[i] = (__bf16)0.0f;

  const __bf16* wbase = wstream + ((size_t)(dir * 8 + w)) * (48 * 64 * 8);
  // LDS chunks 0..16
  #pragma unroll
  for (int c0 = 0; c0 < GRU_NL; ++c0)
    *(bf16x8*)&wlds[((w * GRU_NL + c0) * 64 + lane) * 8] =
        *(const bf16x8*)(wbase + ((size_t)(c0 * 64 + lane)) * 8);
  // VGPR-pinned chunks 17..47 (loaded once; asm makes them non-rematerializable)
  bf16x8 wr[GRU_NV];
  #pragma unroll
  for (int i = 0; i < GRU_NV; ++i)
    wr[i] = *(const bf16x8*)(wbase + ((size_t)((GRU_NL + i) * 64 + lane)) * 8);
  #pragma unroll
  for (int i = 0; i < GRU_NV; ++i) asm volatile("" : "+v"(wr[i]));

  float bhn0 = bhh[dir * 768 + w * 96 + l15 * 6 + 2];
  float bhn1 = bhh[dir * 768 + w * 96 + l15 * 6 + 5];

  const unsigned gofs = (unsigned)(b0 + lq * 4) * (256u * 1536u) + (unsigned)dir * 768u
                      + (unsigned)w * 96u + (unsigned)l15 * 6u;
  const int yrow = tid >> 5, yd0 = (tid & 31) * 8;

  float hprev[2][4] = {};
  int cur = 0;
  __syncthreads();

  for (int s = 0; s < 256; ++s) {
    const int t = dir ? (255 - s) : s;
    // gi prefetch: 3 dwords x 4 batches
    unsigned gw[4][3];
    const unsigned gbase = gofs + (unsigned)t * 1536u;
    #pragma unroll
    for (int r = 0; r < 4; ++r) {
      const unsigned* p = (const unsigned*)(gi + (gbase + (unsigned)r * (256u * 1536u)));
      gw[r][0] = p[0]; gw[r][1] = p[1]; gw[r][2] = p[2];
    }
    // gh = h @ Whh'^T : all 48 chunks resident (17 LDS + 31 VGPR)
    f32x4 acc[2][3] = {};
    const __bf16* hb_ = &hl[cur * (16 * HSTR) + l15 * HSTR + lq * 8];
    #pragma unroll
    for (int ks = 0; ks < 8; ++ks) {
      bf16x8 af = *(const bf16x8*)(hb_ + ks * 32);
      #pragma unroll
      for (int j = 0; j < 6; ++j) {
        const int c = ks * 6 + j;
        bf16x8 wv;
        if (c < GRU_NL) wv = *(const bf16x8*)&wlds[((w * GRU_NL + c) * 64 + lane) * 8];
        else            wv = wr[c - GRU_NL];
        acc[j / 3][j % 3] = __builtin_amdgcn_mfma_f32_16x16x32_bf16(af, wv, acc[j / 3][j % 3], 0, 0, 0);
      }
    }
    // gates + h update (rcp-based)
    #pragma unroll
    for (int dg = 0; dg < 2; ++dg)
      #pragma unroll
      for (int r = 0; r < 4; ++r) {
        float ir, iz, in_;
        if (dg == 0) { ir = bflo(gw[r][0]); iz = bfhi(gw[r][0]); in_ = bflo(gw[r][1]); }
        else         { ir = bfhi(gw[r][1]); iz = bflo(gw[r][2]); in_ = bfhi(gw[r][2]); }
        float bn_ = dg ? bhn1 : bhn0;
        float eR = __expf(-(ir + acc[dg][0][r]));
        float rg = rcp_(1.0f + eR);
        float eZ = __expf(-(iz + acc[dg][1][r]));
        float zg = rcp_(1.0f + eZ);
        float a  = in_ + rg * (acc[dg][2][r] + bn_);
        a = fminf(fmaxf(a, -15.0f), 15.0f);
        float eN = __expf(-2.0f * a);
        float ng = (1.0f - eN) * rcp_(1.0f + eN);
        float h = ng + zg * (hprev[dg][r] - ng);
        hprev[dg][r] = h;
        hl[(cur ^ 1) * (16 * HSTR) + (lq * 4 + r) * HSTR + w * 32 + dg * 16 + l15] = (__bf16)h;
      }
    // raw barrier: order LDS only; global loads/stores stay in flight
    asm volatile("s_waitcnt lgkmcnt(0)\n\ts_barrier" ::: "memory");
    if (ys) {
      bf16x8 hv = *(const bf16x8*)&hl[(cur ^ 1) * (16 * HSTR) + yrow * HSTR + yd0];
      *(bf16x8*)(ys + ((size_t)(b0 + yrow) * 256 + t) * ys_stride + dir * 256 + yd0) = hv;
    }
    cur ^= 1;
  }
  if (!ys) {
    #pragma unroll
    for (int dg = 0; dg < 2; ++dg)
      #pragma unroll
      for (int r = 0; r < 4; ++r)
        out_final[(size_t)(b0 + lq * 4 + r) * 512 + (dir ? 0 : 256) + w * 32 + dg * 16 + l15]
            = hprev[dg][r];
  }
}

// ---------------------------------------------------------------------------
extern "C" void kernel_launch(void* const* d_in, const int* in_sizes, int n_in,
                              void* d_out, int out_size, void* d_ws, size_t ws_size,
                              hipStream_t stream) {
  (void)in_sizes; (void)n_in; (void)out_size; (void)ws_size;
  const float* c  = (const float*)d_in[0];
  const float* q  = (const float*)d_in[1];
  const float* Ws = (const float*)d_in[4];
  const float* w_ih[4] = { (const float*)d_in[5], (const float*)d_in[8],
                           (const float*)d_in[11], (const float*)d_in[14] };
  const float* w_hh[4] = { (const float*)d_in[6], (const float*)d_in[9],
                           (const float*)d_in[12], (const float*)d_in[15] };
  const float* b_l[4]  = { (const float*)d_in[7], (const float*)d_in[10],
                           (const float*)d_in[13], (const float*)d_in[16] };
  const int Kin[4] = {2048, 512, 2560, 512};

  static int lds_set = 0;
  if (!lds_set) {
    hipFuncSetAttribute((const void*)gru_rec,
                        hipFuncAttributeMaxDynamicSharedMemorySize, GRU_LDS_BYTES);
    lds_set = 1;
  }

  char* ws = (char*)d_ws;
  size_t off = 0;
  auto alloc = [&](size_t bytes) -> void* {
    void* p = ws + off; off += (bytes + 255) & ~(size_t)255; return p;
  };
  __bf16* Gbuf = (__bf16*)alloc((size_t)16384 * 2560 * 2);  // [G | M] bf16
  __bf16* gi   = (__bf16*)alloc((size_t)16384 * 1536 * 2);  // gate-packed bf16
  __bf16* m0   = (__bf16*)alloc((size_t)16384 * 512 * 2);
  __bf16* r0   = (__bf16*)alloc((size_t)16384 * 512 * 2);
  __bf16* wihp[4]; __bf16* wstr[4]; float* bihp[4]; float* bhhp[4];
  for (int l = 0; l < 4; ++l) {
    wihp[l] = (__bf16*)alloc((size_t)1536 * Kin[l] * 2);
    wstr[l] = (__bf16*)alloc((size_t)1536 * 256 * 2);   // fragment-major stream
    bihp[l] = (float*)alloc(1536 * 4);
    bhhp[l] = (float*)alloc(1536 * 4);
  }
  float* e_g  = (float*)alloc(4096 * 4);
  float* a_g  = (float*)alloc(16384 * 4);
  float* smax = (float*)alloc(16384 * 4);

  for (int l = 0; l < 4; ++l)
    prep_layer<<<1536, 256, 0, stream>>>(w_ih[l], w_hh[l], b_l[l], Kin[l],
                                         wihp[l], wstr[l], bihp[l], bhhp[l]);
  k_dots<<<5120, 256, 0, stream>>>(c, q, Ws, a_g, e_g);
  k_att_main<<<dim3(2, 64), 512, 0, stream>>>(c, q, Ws, a_g, e_g, smax, Gbuf);
  k_att_tail<<<64, 256, 0, stream>>>(c, smax, Gbuf);

  // layer mod0: G(2048) -> m0
  gemm_bt<<<dim3(128, 12), 256, 0, stream>>>(Gbuf, 2560, wihp[0], bihp[0], gi, 2048);
  gru_rec<<<dim3(4, 2), 512, GRU_LDS_BYTES, stream>>>(gi, wstr[0], bhhp[0], m0, 512, nullptr);
  // layer mod1: m0(512) -> M (into Gbuf cols 2048:2560)
  gemm_bt<<<dim3(128, 12), 256, 0, stream>>>(m0, 512, wihp[1], bihp[1], gi, 512);
  gru_rec<<<dim3(4, 2), 512, GRU_LDS_BYTES, stream>>>(gi, wstr[1], bhhp[1], Gbuf + 2048, 2560, nullptr);
  // layer rep0: [G|M](2560) -> r0
  gemm_bt<<<dim3(128, 12), 256, 0, stream>>>(Gbuf, 2560, wihp[2], bihp[2], gi, 2560);
  gru_rec<<<dim3(4, 2), 512, GRU_LDS_BYTES, stream>>>(gi, wstr[2], bhhp[2], r0, 512, nullptr);
  // layer rep1: r0(512) -> final h only
  gemm_bt<<<dim3(128, 12), 256, 0, stream>>>(r0, 512, wihp[3], bihp[3], gi, 512);
  gru_rec<<<dim3(4, 2), 512, GRU_LDS_BYTES, stream>>>(gi, wstr[3], bhhp[3], nullptr, 0, (float*)d_out);
}